// Round 8
// baseline (274.526 us; speedup 1.0000x reference)
//
#include <hip/hip_runtime.h>

#define CDIM 128
#define NC   8388608
#define XPAD 68   // dw pad: 16B-aligned rows, reads 2-way bank max
#define SPAD 68

// ws layout (float offsets):
//   nrm      @ 0       (960)
//   DT       @ 1024    (122880: DT0@+0, DT1@+8192, DT2@+24576, DT3@+57344)
//   keys     @ 131072  (262144 ints)
//   partials @ 393216  (32768 floats)

// ---- kernel 0: column norms + transposed dict copies ----
__global__ void vq_prep(const float* __restrict__ D0, const float* __restrict__ D1,
                        const float* __restrict__ D2, const float* __restrict__ D3,
                        float* __restrict__ nrm, float* __restrict__ DT) {
  int g = blockIdx.x * 256 + threadIdx.x;
  if (g >= 960) return;
  const float* D; int K, k; float* T;
  if (g < 64)       { D = D0; K = 64;  k = g;       T = DT; }
  else if (g < 192) { D = D1; K = 128; k = g - 64;  T = DT + 8192; }
  else if (g < 448) { D = D2; K = 256; k = g - 192; T = DT + 24576; }
  else              { D = D3; K = 512; k = g - 448; T = DT + 57344; }
  float s = 0.f;
  for (int c = 0; c < 128; ++c) {
    float v = D[c * K + k];
    s = fmaf(v, v, s);
    T[k * 128 + c] = v;
  }
  nrm[g] = s;
}

// per-row criterion update, 4 ascending cols; strict < keeps lowest col
#define UPDR(BI, CI, AV) { \
  cr = fmaf(-2.f, (AV).x, nv.x); if (cr < (BI)) { (BI) = cr; (CI) = cb;     } \
  cr = fmaf(-2.f, (AV).y, nv.y); if (cr < (BI)) { (BI) = cr; (CI) = cb + 1; } \
  cr = fmaf(-2.f, (AV).z, nv.z); if (cr < (BI)) { (BI) = cr; (CI) = cb + 2; } \
  cr = fmaf(-2.f, (AV).w, nv.w); if (cr < (BI)) { (BI) = cr; (CI) = cb + 3; } }

// lex-min merge with shuffle partner
#define SMERGE(BI, CI) { \
  float pb = __shfl_xor((BI), m); int pk = __shfl_xor((CI), m); \
  if (pb < (BI) || (pb == (BI) && pk < (CI))) { (BI) = pb; (CI) = pk; } }

// prefetch one 128x64 dict tile into 8 named float4 regs
#define PF_TILE(SRC, KS, TBN) { \
  const float* base = (SRC) + (TBN) + (t >> 4) * (KS) + (t & 15) * 4; \
  p0 = *(const float4*)(base); \
  p1 = *(const float4*)(base + 16 * (KS)); \
  p2 = *(const float4*)(base + 32 * (KS)); \
  p3 = *(const float4*)(base + 48 * (KS)); \
  p4 = *(const float4*)(base + 64 * (KS)); \
  p5 = *(const float4*)(base + 80 * (KS)); \
  p6 = *(const float4*)(base + 96 * (KS)); \
  p7 = *(const float4*)(base + 112 * (KS)); }

template<int K, int KN, int DICT>
__device__ __forceinline__ void scoreDict(
    const float* __restrict__ D, const float* __restrict__ Dn,
    const float* __restrict__ nseg,
    float (*__restrict__ xt)[XPAD], float (*__restrict__ sd)[SPAD],
    float2 (*__restrict__ cand)[64],
    const int t, const int w, const int r0, const int cg, const int wc,
    int* __restrict__ keys,
    float4& p0, float4& p1, float4& p2, float4& p3,
    float4& p4, float4& p5, float4& p6, float4& p7)
{
  float b0 = 1e30f, b1 = 1e30f, b2 = 1e30f, b3 = 1e30f;
  int   k0 = 0, k1 = 0, k2 = 0, k3 = 0;

  for (int tb = 0; tb < K; tb += 64) {
    __syncthreads();   // everyone done reading sd (prev tile) before overwrite
    // write the prefetched tile from regs into sd
    {
      float* wp = &sd[t >> 4][(t & 15) * 4];
      *(float4*)(wp)             = p0;
      *(float4*)(wp + 16 * SPAD) = p1;
      *(float4*)(wp + 32 * SPAD) = p2;
      *(float4*)(wp + 48 * SPAD) = p3;
      *(float4*)(wp + 64 * SPAD) = p4;
      *(float4*)(wp + 80 * SPAD) = p5;
      *(float4*)(wp + 96 * SPAD) = p6;
      *(float4*)(wp + 112 * SPAD) = p7;
    }
    __syncthreads();

    // issue prefetch of the NEXT tile (in-dict, or next dict's tile 0);
    // its latency hides under the 128-c compute below
    if (tb + 64 < K) {
      PF_TILE(D, K, tb + 64)
    } else {
      PF_TILE(Dn, KN, 0)
    }

    float4 a0 = make_float4(0.f, 0.f, 0.f, 0.f);
    float4 a1 = a0, a2 = a0, a3 = a0;
    #pragma unroll 4
    for (int c = 0; c < 128; ++c) {
      float4 xv = *(const float4*)&xt[c][r0];   // 4 rows
      float4 dv = *(const float4*)&sd[c][wc];   // 4 cols
      a0.x = fmaf(xv.x, dv.x, a0.x); a0.y = fmaf(xv.x, dv.y, a0.y);
      a0.z = fmaf(xv.x, dv.z, a0.z); a0.w = fmaf(xv.x, dv.w, a0.w);
      a1.x = fmaf(xv.y, dv.x, a1.x); a1.y = fmaf(xv.y, dv.y, a1.y);
      a1.z = fmaf(xv.y, dv.z, a1.z); a1.w = fmaf(xv.y, dv.w, a1.w);
      a2.x = fmaf(xv.z, dv.x, a2.x); a2.y = fmaf(xv.z, dv.y, a2.y);
      a2.z = fmaf(xv.z, dv.z, a2.z); a2.w = fmaf(xv.z, dv.w, a2.w);
      a3.x = fmaf(xv.w, dv.x, a3.x); a3.y = fmaf(xv.w, dv.y, a3.y);
      a3.z = fmaf(xv.w, dv.z, a3.z); a3.w = fmaf(xv.w, dv.w, a3.w);
    }

    const int cb = tb + wc;
    const float4 nv = *(const float4*)(nseg + cb);
    float cr;
    UPDR(b0, k0, a0)
    UPDR(b1, k1, a1)
    UPDR(b2, k2, a2)
    UPDR(b3, k3, a3)
  }

  // merge the 4 col-groups (lanes differing in low 2 bits) per row, lex order
  #pragma unroll
  for (int m = 1; m < 4; m <<= 1) {
    SMERGE(b0, k0) SMERGE(b1, k1) SMERGE(b2, k2) SMERGE(b3, k3)
  }
  if (cg == 0) {
    cand[w][r0 + 0] = make_float2(b0, __int_as_float(k0));
    cand[w][r0 + 1] = make_float2(b1, __int_as_float(k1));
    cand[w][r0 + 2] = make_float2(b2, __int_as_float(k2));
    cand[w][r0 + 3] = make_float2(b3, __int_as_float(k3));
  }
  __syncthreads();
  if (t < 64) {
    float2 mm = cand[0][t]; float mb = mm.x; int mk = __float_as_int(mm.y);
    #pragma unroll
    for (int w2 = 1; w2 < 4; ++w2) {
      float2 c2 = cand[w2][t]; int kk = __float_as_int(c2.y);
      if (c2.x < mb || (c2.x == mb && kk < mk)) { mb = c2.x; mk = kk; }
    }
    keys[((blockIdx.x * 64 + t) << 2) | DICT] = mk;
  }
}

// ---- kernel 1: register-tiled LDS GEMM scoring with reg-prefetch pipeline ----
__global__ __launch_bounds__(256, 2) void vq_main(
    const float* __restrict__ x,
    const float* __restrict__ D0, const float* __restrict__ D1,
    const float* __restrict__ D2, const float* __restrict__ D3,
    const float* __restrict__ nrm, int* __restrict__ keys)
{
  __shared__ float  xt[128][XPAD];   // [c][row]  ~34.8 KB
  __shared__ float  sd[128][SPAD];   // [c][col]  ~34.8 KB
  __shared__ float2 cand[4][64];     // 2 KB

  const int t  = threadIdx.x;
  const int l  = t & 63;
  const int w  = t >> 6;
  const int r0 = (l >> 2) * 4;       // lane's 4 rows
  const int cg = l & 3;
  const int wc = w * 16 + cg * 4;    // lane's 4 cols within 64-col tile

  // prefetch dict0 tile0 into regs (overlaps with xt staging below)
  float4 p0, p1, p2, p3, p4, p5, p6, p7;
  PF_TILE(D0, 64, 0)

  // stage x transposed: [row][c] global -> [c][row] LDS
  const float4* __restrict__ xg = (const float4*)x + (size_t)blockIdx.x * 2048;
  #pragma unroll
  for (int j = 0; j < 8; ++j) {
    int f = j * 256 + t;             // row = f>>5, c4 = f&31
    float4 v = xg[f];
    int row = f >> 5, c0 = (f & 31) * 4;
    xt[c0 + 0][row] = v.x;
    xt[c0 + 1][row] = v.y;
    xt[c0 + 2][row] = v.z;
    xt[c0 + 3][row] = v.w;
  }
  // scoreDict's leading __syncthreads() covers the staging barrier

  scoreDict< 64, 128, 0>(D0, D1, nrm +   0, xt, sd, cand, t, w, r0, cg, wc, keys,
                         p0, p1, p2, p3, p4, p5, p6, p7);
  scoreDict<128, 256, 1>(D1, D2, nrm +  64, xt, sd, cand, t, w, r0, cg, wc, keys,
                         p0, p1, p2, p3, p4, p5, p6, p7);
  scoreDict<256, 512, 2>(D2, D3, nrm + 192, xt, sd, cand, t, w, r0, cg, wc, keys,
                         p0, p1, p2, p3, p4, p5, p6, p7);
  scoreDict<512, 512, 3>(D3, D3, nrm + 448, xt, sd, cand, t, w, r0, cg, wc, keys,
                         p0, p1, p2, p3, p4, p5, p6, p7);
}

// ---- kernel 2: gather winners (coalesced via DT), write out + loss partials ----
__global__ __launch_bounds__(256, 8) void vq_merge(
    const float* __restrict__ x, const float* __restrict__ DT,
    const int* __restrict__ keys,
    const float* __restrict__ alpha_p, const float* __restrict__ gamma_p,
    float* __restrict__ out, float* __restrict__ partials)
{
  __shared__ int kk[2][4];
  __shared__ float wr[4];
  const int t = threadIdx.x;
  const int c = t & 127, rs = t >> 7;
  const int row0 = blockIdx.x * 2;
  if (t < 8) {
    int r = t >> 2, d = t & 3;
    kk[r][d] = keys[((row0 + r) << 2) | d];
  }
  __syncthreads();
  const int row = row0 + rs;
  const float a = alpha_p[0];
  const float g0 = gamma_p[0], g1 = gamma_p[1], g2 = gamma_p[2], g3 = gamma_p[3];
  const float xv = x[(size_t)row * CDIM + c];
  const float d0 = DT[         kk[rs][0] * 128 + c];
  const float d1 = DT[ 8192  + kk[rs][1] * 128 + c];
  const float d2 = DT[ 24576 + kk[rs][2] * 128 + c];
  const float d3 = DT[ 57344 + kk[rs][3] * 128 + c];
  out[(size_t)row * CDIM + c] = a * (g0*d0 + g1*d1 + g2*d2 + g3*d3);
  float e0 = fmaf(-a, d0, xv), e1 = fmaf(-a, d1, xv);
  float e2 = fmaf(-a, d2, xv), e3 = fmaf(-a, d3, xv);
  float lc = g0*e0*e0 + g1*e1*e1 + g2*e2*e2 + g3*e3*e3;
  #pragma unroll
  for (int off = 32; off > 0; off >>= 1) lc += __shfl_down(lc, off);
  if ((t & 63) == 0) wr[t >> 6] = lc;
  __syncthreads();
  if (t == 0) partials[blockIdx.x] = wr[0] + wr[1] + wr[2] + wr[3];
}

// ---- kernel 3: final deterministic loss reduction ----
__global__ void vq_loss(const float* __restrict__ partials, float* __restrict__ lossp) {
  __shared__ float wr[4];
  const int t = threadIdx.x;
  float v = 0.f;
  #pragma unroll 8
  for (int i = 0; i < 128; ++i) v += partials[i * 256 + t];
  #pragma unroll
  for (int off = 32; off > 0; off >>= 1) v += __shfl_down(v, off);
  if ((t & 63) == 0) wr[t >> 6] = v;
  __syncthreads();
  if (t == 0) lossp[0] = (wr[0] + wr[1] + wr[2] + wr[3]) * (1.25f / 8388608.f);
}

extern "C" void kernel_launch(void* const* d_in, const int* in_sizes, int n_in,
                              void* d_out, int out_size, void* d_ws, size_t ws_size,
                              hipStream_t stream) {
  const float* x  = (const float*)d_in[0];
  const float* D0 = (const float*)d_in[1];
  const float* D1 = (const float*)d_in[2];
  const float* D2 = (const float*)d_in[3];
  const float* D3 = (const float*)d_in[4];
  const float* alpha = (const float*)d_in[5];
  const float* gamma = (const float*)d_in[6];
  float* out = (float*)d_out;

  float* ws = (float*)d_ws;
  float* nrm = ws;                        // 960
  float* DT  = ws + 1024;                 // 122880
  int*  keys = (int*)(ws + 131072);       // 262144 ints
  float* partials = ws + 393216;          // 32768

  vq_prep<<<4, 256, 0, stream>>>(D0, D1, D2, D3, nrm, DT);
  vq_main<<<1024, 256, 0, stream>>>(x, D0, D1, D2, D3, nrm, keys);
  vq_merge<<<32768, 256, 0, stream>>>(x, DT, keys, alpha, gamma, out, partials);
  vq_loss<<<1, 256, 0, stream>>>(partials, out + NC);
}